// Round 1
// baseline (268.272 us; speedup 1.0000x reference)
//
#include <hip/hip_runtime.h>

#define N_NODES 50000
#define DIM 256
#define NEG 0.2f
#define LN_EPS 1e-5f
#define BM 64
#define BK 16

// ---------------- mask kernels ----------------
__global__ void zero_masks(unsigned int* m, int words) {
    int i = blockIdx.x * blockDim.x + threadIdx.x;
    if (i < words) m[i] = 0u;
}

__global__ void scatter_masks(const int* __restrict__ d0, const int* __restrict__ d1,
                              const int* __restrict__ d2, int E, unsigned char* __restrict__ m) {
    int i = blockIdx.x * blockDim.x + threadIdx.x;
    if (i >= 3 * E) return;
    const int* d;
    int base, e;
    if (i >= 2 * E)      { d = d2; e = i - 2 * E; base = 2 * N_NODES; }
    else if (i >= E)     { d = d1; e = i - E;     base = N_NODES; }
    else                 { d = d0; e = i;         base = 0; }
    m[base + d[e]] = (unsigned char)1;   // idempotent racy store: benign
}

// ---------------- fused GEMM + epilogue ----------------
// v = feat @ Wr + br  (rows BM per block, all 256 cols)
// out = LN(relu(v * w)),  w from analytic metapath-softmax collapse.
__global__ __launch_bounds__(256) void fused_gemm(
    const float* __restrict__ feat, const float* __restrict__ Wr, const float* __restrict__ br,
    const float* __restrict__ rel_q, const float* __restrict__ rel_k,
    const float* __restrict__ gamma, const float* __restrict__ beta,
    const unsigned char* __restrict__ mask, float* __restrict__ out)
{
    __shared__ float As[BM][BK + 4];   // pad to 20 floats: 16B-aligned rows, conflict-free
    __shared__ float Ws[BK][DIM];

    const int tid = threadIdx.x;
    const int tx = tid & 15;           // col group: cols h*64 + tx*4 + j  (4 cols in each head)
    const int ty = tid >> 4;           // row group: rows ty*4 + i
    const int row0 = blockIdx.x * BM;

    // global-load assignments
    const int lr = tid >> 2;           // feat: row within tile (0..63)
    const int lk = (tid & 3) * 4;      // feat: k offset {0,4,8,12}
    const int wk = tid >> 6;           // Wr: base k (0..3), +i*4
    const int wn = (tid & 63) * 4;     // Wr: col

    float acc[4][16];
    #pragma unroll
    for (int h = 0; h < 4; ++h) {
        const float4 b4 = *(const float4*)(br + h * 64 + tx * 4);
        #pragma unroll
        for (int i = 0; i < 4; ++i) {
            acc[i][h * 4 + 0] = b4.x; acc[i][h * 4 + 1] = b4.y;
            acc[i][h * 4 + 2] = b4.z; acc[i][h * 4 + 3] = b4.w;
        }
    }

    int frow = row0 + lr;
    if (frow >= N_NODES) frow = N_NODES - 1;           // clamp: junk rows never stored
    const float* fptr = feat + (size_t)frow * DIM + lk;

    for (int k0 = 0; k0 < DIM; k0 += BK) {
        float4 fa = *(const float4*)(fptr + k0);
        float4 wa[4];
        #pragma unroll
        for (int i = 0; i < 4; ++i)
            wa[i] = *(const float4*)(Wr + (size_t)(k0 + wk + i * 4) * DIM + wn);

        __syncthreads();
        *(float4*)&As[lr][lk] = fa;
        #pragma unroll
        for (int i = 0; i < 4; ++i)
            *(float4*)&Ws[wk + i * 4][wn] = wa[i];
        __syncthreads();

        #pragma unroll
        for (int k = 0; k < BK; ++k) {
            float av[4];
            #pragma unroll
            for (int i = 0; i < 4; ++i) av[i] = As[ty * 4 + i][k];
            #pragma unroll
            for (int h = 0; h < 4; ++h) {
                const float4 w4 = *(const float4*)&Ws[k][h * 64 + tx * 4];
                #pragma unroll
                for (int i = 0; i < 4; ++i) {
                    acc[i][h * 4 + 0] += av[i] * w4.x;
                    acc[i][h * 4 + 1] += av[i] * w4.y;
                    acc[i][h * 4 + 2] += av[i] * w4.z;
                    acc[i][h * 4 + 3] += av[i] * w4.w;
                }
            }
        }
    }

    // ---- fused epilogue: per row (16 lanes with same ty hold the full 256 cols) ----
    float4 rq4[4], rk4[4];
    #pragma unroll
    for (int h = 0; h < 4; ++h) {
        rq4[h] = *(const float4*)(rel_q + h * 64 + tx * 4);
        rk4[h] = *(const float4*)(rel_k + h * 64 + tx * 4);
    }

    #pragma unroll
    for (int i = 0; i < 4; ++i) {
        const int row = row0 + ty * 4 + i;
        const bool valid = row < N_NODES;              // uniform within the 16-lane group

        float qp[4], kp[4];
        #pragma unroll
        for (int h = 0; h < 4; ++h) {
            qp[h] = acc[i][h*4+0]*rq4[h].x + acc[i][h*4+1]*rq4[h].y
                  + acc[i][h*4+2]*rq4[h].z + acc[i][h*4+3]*rq4[h].w;
            kp[h] = acc[i][h*4+0]*rk4[h].x + acc[i][h*4+1]*rk4[h].y
                  + acc[i][h*4+2]*rk4[h].z + acc[i][h*4+3]*rk4[h].w;
        }
        #pragma unroll
        for (int ofs = 1; ofs < 16; ofs <<= 1) {
            #pragma unroll
            for (int h = 0; h < 4; ++h) {
                qp[h] += __shfl_xor(qp[h], ofs);
                kp[h] += __shfl_xor(kp[h], ofs);
            }
        }

        int cnt = 0;
        if (valid)
            cnt = (int)mask[row] + (int)mask[N_NODES + row] + (int)mask[2 * N_NODES + row];

        float wgt[4];
        #pragma unroll
        for (int h = 0; h < 4; ++h) {
            const float q = qp[h];
            const float qk = q + kp[h];
            const float a = q  > 0.f ? q  : NEG * q;    // inactive-relation logit
            const float b = qk > 0.f ? qk : NEG * qk;   // active/self logit
            const float mx = fmaxf(a, b);
            const float eb = (float)(cnt + 1) * __expf(b - mx);
            const float ea = (float)(3 - cnt) * __expf(a - mx);
            wgt[h] = eb / (eb + ea);
        }

        float o[16], sum = 0.f, ssq = 0.f;
        #pragma unroll
        for (int h = 0; h < 4; ++h) {
            #pragma unroll
            for (int j = 0; j < 4; ++j) {
                float v = acc[i][h * 4 + j] * wgt[h];
                v = fmaxf(v, 0.f);                      // ReLU
                o[h * 4 + j] = v;
                sum += v; ssq += v * v;
            }
        }
        #pragma unroll
        for (int ofs = 1; ofs < 16; ofs <<= 1) {
            sum += __shfl_xor(sum, ofs);
            ssq += __shfl_xor(ssq, ofs);
        }
        const float mu = sum * (1.f / 256.f);
        const float var = ssq * (1.f / 256.f) - mu * mu;
        const float rstd = rsqrtf(var + LN_EPS);

        if (valid) {
            #pragma unroll
            for (int h = 0; h < 4; ++h) {
                const float4 g = *(const float4*)(gamma + h * 64 + tx * 4);
                const float4 bb = *(const float4*)(beta + h * 64 + tx * 4);
                float4 r;
                r.x = (o[h*4+0] - mu) * rstd * g.x + bb.x;
                r.y = (o[h*4+1] - mu) * rstd * g.y + bb.y;
                r.z = (o[h*4+2] - mu) * rstd * g.z + bb.z;
                r.w = (o[h*4+3] - mu) * rstd * g.w + bb.w;
                *(float4*)(out + (size_t)row * DIM + h * 64 + tx * 4) = r;
            }
        }
    }
}

extern "C" void kernel_launch(void* const* d_in, const int* in_sizes, int n_in,
                              void* d_out, int out_size, void* d_ws, size_t ws_size,
                              hipStream_t stream) {
    const float* feat  = (const float*)d_in[0];
    // d_in[1] (Wl), d_in[2] (bl), d_in[5] (attn_l), d_in[6] (attn_r), edge_src_* : unused (dead code)
    const float* Wr    = (const float*)d_in[3];
    const float* br    = (const float*)d_in[4];
    const float* rel_q = (const float*)d_in[7];
    const float* rel_k = (const float*)d_in[8];
    const float* gamma = (const float*)d_in[9];
    const float* beta  = (const float*)d_in[10];
    const int* dst0 = (const int*)d_in[12];
    const int* dst1 = (const int*)d_in[14];
    const int* dst2 = (const int*)d_in[16];
    const int E = in_sizes[12];

    unsigned char* mask = (unsigned char*)d_ws;        // 3*N bytes
    const int words = (3 * N_NODES + 3) / 4;

    zero_masks<<<(words + 255) / 256, 256, 0, stream>>>((unsigned int*)d_ws, words);
    scatter_masks<<<(3 * E + 255) / 256, 256, 0, stream>>>(dst0, dst1, dst2, E, mask);
    fused_gemm<<<(N_NODES + BM - 1) / BM, 256, 0, stream>>>(
        feat, Wr, br, rel_q, rel_k, gamma, beta, mask, (float*)d_out);
}

// Round 2
// 216.373 us; speedup vs baseline: 1.2399x; 1.2399x over previous
//
#include <hip/hip_runtime.h>

#define N_NODES 50000
#define DIM 256
#define NEG 0.2f
#define LN_EPS 1e-5f

typedef __attribute__((ext_vector_type(8))) short short8;   // 8 x bf16 (4 VGPRs)
typedef __attribute__((ext_vector_type(4))) float f32x4;    // MFMA accumulator

__device__ __forceinline__ unsigned short f2bf(float x) {   // RNE fp32 -> bf16
    unsigned int u = __builtin_bit_cast(unsigned int, x);
    u += 0x7fffu + ((u >> 16) & 1u);
    return (unsigned short)(u >> 16);
}

// ---------- Wr (256x256 fp32) -> WrT bf16 [m][k] ----------
__global__ __launch_bounds__(256) void wr_to_bf16T(const float* __restrict__ Wr,
                                                   unsigned short* __restrict__ WrT) {
    __shared__ float tile[64][65];
    const int bx = (blockIdx.x & 3) * 64;    // k block
    const int by = (blockIdx.x >> 2) * 64;   // m block
    const int c = threadIdx.x & 63;
    const int r0 = threadIdx.x >> 6;
    #pragma unroll
    for (int i = 0; i < 16; ++i) {
        int r = r0 * 16 + i;
        tile[r][c] = Wr[(size_t)(bx + r) * DIM + by + c];   // coalesced read
    }
    __syncthreads();
    #pragma unroll
    for (int i = 0; i < 16; ++i) {
        int r = r0 * 16 + i;
        WrT[(size_t)(by + r) * DIM + bx + c] = f2bf(tile[c][r]);  // coalesced write
    }
}

// ---------- edge-dst presence masks (read-filtered scatter) ----------
__global__ void scatter_masks(const int* __restrict__ d0, const int* __restrict__ d1,
                              const int* __restrict__ d2, int E, unsigned char* __restrict__ m) {
    int i = blockIdx.x * blockDim.x + threadIdx.x;
    if (i >= 3 * E) return;
    const int* d;
    int base, e;
    if (i >= 2 * E)      { d = d2; e = i - 2 * E; base = 2 * N_NODES; }
    else if (i >= E)     { d = d1; e = i - E;     base = N_NODES; }
    else                 { d = d0; e = i;         base = 0; }
    const int idx = base + d[e];
    if (m[idx] == 0) m[idx] = (unsigned char)1;   // filter: cut same-line store storms
}

// ---------- fused MFMA GEMM + analytic-collapse epilogue ----------
// Each wave: 16 nodes (lane&15) x 256 out-cols (16 m-tiles). No LDS, no barriers.
__global__ __launch_bounds__(256) void fused_mfma(
    const float* __restrict__ feat, const unsigned short* __restrict__ WrT,
    const float* __restrict__ br, const float* __restrict__ rel_q,
    const float* __restrict__ rel_k, const float* __restrict__ gamma,
    const float* __restrict__ beta_p, const unsigned char* __restrict__ mask,
    float* __restrict__ out)
{
    const int lane = threadIdx.x & 63;
    const int wave = threadIdx.x >> 6;
    const int ln = lane & 15;      // node within wave / MFMA n
    const int quad = lane >> 4;    // MFMA k-quad & D-row-quad
    int node = blockIdx.x * 64 + wave * 16 + ln;
    const bool valid = node < N_NODES;
    if (!valid) node = N_NODES - 1;              // clamp: loads safe, store guarded

    f32x4 acc[16];
    #pragma unroll
    for (int mt = 0; mt < 16; ++mt) acc[mt] = (f32x4){0.f, 0.f, 0.f, 0.f};

    const float* fptr = feat + (size_t)node * DIM + quad * 8;
    const unsigned short* aptr = WrT + (size_t)ln * DIM + quad * 8;

    float4 fb0 = *(const float4*)(fptr);
    float4 fb1 = *(const float4*)(fptr + 4);

    #pragma unroll 1
    for (int k0 = 0; k0 < DIM; k0 += 32) {
        short8 bfrag;
        bfrag[0] = (short)f2bf(fb0.x); bfrag[1] = (short)f2bf(fb0.y);
        bfrag[2] = (short)f2bf(fb0.z); bfrag[3] = (short)f2bf(fb0.w);
        bfrag[4] = (short)f2bf(fb1.x); bfrag[5] = (short)f2bf(fb1.y);
        bfrag[6] = (short)f2bf(fb1.z); bfrag[7] = (short)f2bf(fb1.w);
        if (k0 + 32 < DIM) {                      // prefetch next feat chunk (HBM)
            fb0 = *(const float4*)(fptr + k0 + 32);
            fb1 = *(const float4*)(fptr + k0 + 36);
        }
        #pragma unroll
        for (int mt = 0; mt < 16; ++mt) {
            const short8 afrag = *(const short8*)(aptr + (size_t)(mt * 16) * DIM + k0);
            acc[mt] = __builtin_amdgcn_mfma_f32_16x16x32_bf16(afrag, bfrag, acc[mt], 0, 0, 0);
        }
    }

    // ---- epilogue: bias, per-head dots, softmax weight, ReLU, LayerNorm ----
    // Lane holds cols m = mt*16 + quad*4 + r for this node; node also on lanes ^16,^32.
    float qp[4] = {0.f, 0.f, 0.f, 0.f}, kp[4] = {0.f, 0.f, 0.f, 0.f};
    #pragma unroll
    for (int mt = 0; mt < 16; ++mt) {
        const int cbase = mt * 16 + quad * 4;
        const float4 bb = *(const float4*)(br + cbase);
        acc[mt][0] += bb.x; acc[mt][1] += bb.y; acc[mt][2] += bb.z; acc[mt][3] += bb.w;
        const float4 rq = *(const float4*)(rel_q + cbase);
        const float4 rk = *(const float4*)(rel_k + cbase);
        const int h = mt >> 2;
        qp[h] += acc[mt][0] * rq.x + acc[mt][1] * rq.y + acc[mt][2] * rq.z + acc[mt][3] * rq.w;
        kp[h] += acc[mt][0] * rk.x + acc[mt][1] * rk.y + acc[mt][2] * rk.z + acc[mt][3] * rk.w;
    }
    #pragma unroll
    for (int h = 0; h < 4; ++h) {
        qp[h] += __shfl_xor(qp[h], 16); qp[h] += __shfl_xor(qp[h], 32);
        kp[h] += __shfl_xor(kp[h], 16); kp[h] += __shfl_xor(kp[h], 32);
    }

    const int cnt = (int)mask[node] + (int)mask[N_NODES + node] + (int)mask[2 * N_NODES + node];

    float wgt[4];
    #pragma unroll
    for (int h = 0; h < 4; ++h) {
        const float q = qp[h];
        const float qk = q + kp[h];
        const float a = q  > 0.f ? q  : NEG * q;    // inactive-relation logit
        const float b = qk > 0.f ? qk : NEG * qk;   // active/self logit
        const float mx = fmaxf(a, b);
        const float eb = (float)(cnt + 1) * __expf(b - mx);
        const float ea = (float)(3 - cnt) * __expf(a - mx);
        wgt[h] = eb / (eb + ea);
    }

    float sum = 0.f, ssq = 0.f;
    #pragma unroll
    for (int mt = 0; mt < 16; ++mt) {
        const float w = wgt[mt >> 2];
        #pragma unroll
        for (int r = 0; r < 4; ++r) {
            float v = fmaxf(acc[mt][r] * w, 0.f);   // ReLU
            acc[mt][r] = v;
            sum += v; ssq += v * v;
        }
    }
    sum += __shfl_xor(sum, 16); sum += __shfl_xor(sum, 32);
    ssq += __shfl_xor(ssq, 16); ssq += __shfl_xor(ssq, 32);
    const float mu = sum * (1.f / 256.f);
    const float var = ssq * (1.f / 256.f) - mu * mu;
    const float rstd = rsqrtf(var + LN_EPS);

    if (valid) {
        float* optr = out + (size_t)node * DIM;
        #pragma unroll
        for (int mt = 0; mt < 16; ++mt) {
            const int cbase = mt * 16 + quad * 4;
            const float4 g = *(const float4*)(gamma + cbase);
            const float4 b = *(const float4*)(beta_p + cbase);
            float4 r;
            r.x = (acc[mt][0] - mu) * rstd * g.x + b.x;
            r.y = (acc[mt][1] - mu) * rstd * g.y + b.y;
            r.z = (acc[mt][2] - mu) * rstd * g.z + b.z;
            r.w = (acc[mt][3] - mu) * rstd * g.w + b.w;
            *(float4*)(optr + cbase) = r;
        }
    }
}

extern "C" void kernel_launch(void* const* d_in, const int* in_sizes, int n_in,
                              void* d_out, int out_size, void* d_ws, size_t ws_size,
                              hipStream_t stream) {
    const float* feat  = (const float*)d_in[0];
    // d_in[1] Wl, d_in[2] bl, d_in[5] attn_l, d_in[6] attn_r, edge_src_*: dead code
    const float* Wr    = (const float*)d_in[3];
    const float* br    = (const float*)d_in[4];
    const float* rel_q = (const float*)d_in[7];
    const float* rel_k = (const float*)d_in[8];
    const float* gamma = (const float*)d_in[9];
    const float* beta  = (const float*)d_in[10];
    const int* dst0 = (const int*)d_in[12];
    const int* dst1 = (const int*)d_in[14];
    const int* dst2 = (const int*)d_in[16];
    const int E = in_sizes[12];

    unsigned short* WrT = (unsigned short*)d_ws;                    // 128 KiB
    unsigned char* mask = (unsigned char*)d_ws + DIM * DIM * 2;     // 3*N bytes

    wr_to_bf16T<<<16, 256, 0, stream>>>(Wr, WrT);
    hipMemsetAsync(mask, 0, 3 * N_NODES, stream);
    scatter_masks<<<(3 * E + 255) / 256, 256, 0, stream>>>(dst0, dst1, dst2, E, mask);
    fused_mfma<<<(N_NODES + 63) / 64, 256, 0, stream>>>(
        feat, WrT, br, rel_q, rel_k, gamma, beta, mask, (float*)d_out);
}